// Round 2
// baseline (1971.506 us; speedup 1.0000x reference)
//
#include <hip/hip_runtime.h>

// LinearREncoder: concat(x,y) -> relu(W1)->relu(W2)->(aggregate)->W3 -> masked mean
// B=64 N=512 XD=YD=128 DIN=256 HD=4096 RD=1024, M=B*N=32768 tokens.
// Strategy: bf16 MFMA (16x16x32) m97-style 128x128x64 GEMMs; layer-3 applied
// AFTER masked-sum (linearity); prefix-mask M-tile skip; H1 chunked 4x (ws ~125MB).
// R2 fix: mask arrives as int32 (harness: bool -> int), not bytes. len=0 batches
// from the byte-parse produced inf*0=NaN in sn_k.

using u16 = unsigned short;
typedef float f32x4 __attribute__((ext_vector_type(4)));
typedef short s16x8 __attribute__((ext_vector_type(8)));

__device__ __forceinline__ u16 f2bf(float f) {
  union { float f; unsigned u; } v; v.f = f;
  unsigned r = (v.u + 0x7fffu + ((v.u >> 16) & 1u)) >> 16;  // RNE
  return (u16)r;
}

// ---------------- prep kernels ----------------

// lens[b] = sum of mask ints (harness passes bool as int32, values 0/1)
__global__ void count_k(const int* __restrict__ mask, int* __restrict__ lens) {
  int b = blockIdx.x, l = threadIdx.x;  // 64 blocks x 64 threads
  const int4* row = (const int4*)(mask + (size_t)b * 512);
  int4 v0 = row[l];          // ints 4l..4l+3
  int4 v1 = row[l + 64];     // ints 256+4l..
  int s = v0.x + v0.y + v0.z + v0.w + v1.x + v1.y + v1.z + v1.w;
  #pragma unroll
  for (int o = 32; o; o >>= 1) s += __shfl_down(s, o);
  if (l == 0) lens[b] = s;
}

// A[m][0:128]=bf16(x[m]), A[m][128:256]=bf16(y[m])
__global__ void build_a(const float* __restrict__ x, const float* __restrict__ y,
                        u16* __restrict__ A) {
  int i4 = blockIdx.x * 256 + threadIdx.x;  // one float4 each; grid 8192
  int e = i4 * 4;
  int m = e >> 8, c = e & 255;
  const float* src = (c < 128) ? (x + (size_t)m * 128 + c)
                               : (y + (size_t)m * 128 + (c - 128));
  float4 v = *(const float4*)src;
  ushort4 o;
  o.x = f2bf(v.x); o.y = f2bf(v.y); o.z = f2bf(v.z); o.w = f2bf(v.w);
  *(ushort4*)&A[e] = o;
}

// out[C][R] bf16 = transpose of in[R][C] f32
__global__ void transpose_k(const float* __restrict__ in, u16* __restrict__ out,
                            int R, int C) {
  __shared__ float tile[32][33];
  int c0 = blockIdx.x * 32, r0 = blockIdx.y * 32;
  int tx = threadIdx.x;
  #pragma unroll
  for (int yy = threadIdx.y; yy < 32; yy += 8)
    tile[yy][tx] = in[(size_t)(r0 + yy) * C + c0 + tx];
  __syncthreads();
  #pragma unroll
  for (int yy = threadIdx.y; yy < 32; yy += 8)
    out[(size_t)(c0 + yy) * R + r0 + tx] = f2bf(tile[tx][yy]);
}

// Sn[m][k] = bf16(S[m][k] / len[m]) for m<64, else 0  (S rows 64..127 are zeroed)
__global__ void sn_k(const float* __restrict__ S, const int* __restrict__ lens,
                     u16* __restrict__ Sn) {
  int i4 = blockIdx.x * 256 + threadIdx.x;  // grid 512: 128*4096/4 float4s
  int e = i4 * 4;
  int m = e >> 12;
  float inv = (m < 64) ? (1.0f / (float)lens[m]) : 0.0f;
  float4 v = *(const float4*)(S + e);
  ushort4 o;
  o.x = f2bf(v.x * inv); o.y = f2bf(v.y * inv);
  o.z = f2bf(v.z * inv); o.w = f2bf(v.w * inv);
  *(ushort4*)&Sn[e] = o;
}

// ---------------- main GEMM ----------------
// C[128x128] tile = A[128xK] @ BT[NxK]^T.  BK=64, 4 waves in 2x2, 64x64/wave.
// MODE 0: Hout[m][n] = bf16(relu(acc + bias[n]))            (layer 1)
// MODE 1: Sout[b][n] += sum over valid rows of relu(acc+bias[n])  (layer 2 + pool)
// MODE 2: Fout[m][n] = acc + bias[n], rows < 64 only         (layer 3)
template <int MODE>
__global__ __launch_bounds__(256) void gemm_k(
    const u16* __restrict__ A, int lda, const u16* __restrict__ BT, int ldb,
    const float* __restrict__ bias, u16* __restrict__ Hout,
    float* __restrict__ Sout, float* __restrict__ Fout,
    const int* __restrict__ lens, int K, int Nld, int m_row_base) {
  __shared__ union {
    struct { u16 a[128 * 64]; u16 b[128 * 64]; } st;  // 16KB + 16KB
    u16 outT[128 * 136];                              // MODE0 repack (pad 8)
    float colsum[128];                                // MODE1 reduce
  } sm;

  const int mt = blockIdx.y;
  const int n0 = blockIdx.x * 128;
  int lenb = 1 << 30;
  int bidx = 0;
  if constexpr (MODE < 2) {
    const int gm0 = m_row_base + mt * 128;
    bidx = gm0 >> 9;              // batch id (512 tokens/batch)
    const int m0b = gm0 & 511;    // tile start within batch
    const int len = lens[bidx];
    if (m0b >= len) return;       // whole tile masked out -> skip
    lenb = len - m0b;             // rows < lenb are valid
  }

  const int tid = threadIdx.x;
  const int wave = tid >> 6;
  const int lane = tid & 63;
  const int wm = wave >> 1, wn = wave & 1;
  const int quad = lane >> 4, l15 = lane & 15;

  f32x4 acc[4][4];
  #pragma unroll
  for (int i = 0; i < 4; i++)
    #pragma unroll
    for (int j = 0; j < 4; j++) acc[i][j] = (f32x4){0.f, 0.f, 0.f, 0.f};

  // Staging: 1024 16B chunks per tile; chunk ci holds global (row=ci>>3,
  // kchunk=(ci&7)^(row&7)) -> XOR swizzle kills ds_read_b128 bank conflicts.
  const u16* ag[4]; const u16* bg[4];
  #pragma unroll
  for (int il = 0; il < 4; ++il) {
    int ci = (wave * 4 + il) * 64 + lane;
    int m = ci >> 3, c = (ci & 7) ^ (m & 7);
    ag[il] = A + (size_t)(mt * 128 + m) * lda + c * 8;
    bg[il] = BT + (size_t)(n0 + m) * ldb + c * 8;
  }

  for (int kt = 0; kt < K; kt += 64) {
    #pragma unroll
    for (int il = 0; il < 4; ++il)
      __builtin_amdgcn_global_load_lds(
          (const __attribute__((address_space(1))) void*)(ag[il] + kt),
          (__attribute__((address_space(3))) void*)(&sm.st.a[(wave * 4 + il) * 512]),
          16, 0, 0);
    #pragma unroll
    for (int il = 0; il < 4; ++il)
      __builtin_amdgcn_global_load_lds(
          (const __attribute__((address_space(1))) void*)(bg[il] + kt),
          (__attribute__((address_space(3))) void*)(&sm.st.b[(wave * 4 + il) * 512]),
          16, 0, 0);
    __syncthreads();
    #pragma unroll
    for (int s = 0; s < 2; ++s) {  // two k=32 steps
      s16x8 af[4], bf[4];
      #pragma unroll
      for (int i = 0; i < 4; i++) {
        int m = wm * 64 + i * 16 + l15;
        int c = s * 4 + quad;
        af[i] = *(const s16x8*)&sm.st.a[(m * 8 + (c ^ (m & 7))) * 8];
      }
      #pragma unroll
      for (int j = 0; j < 4; j++) {
        int n = wn * 64 + j * 16 + l15;
        int c = s * 4 + quad;
        bf[j] = *(const s16x8*)&sm.st.b[(n * 8 + (c ^ (n & 7))) * 8];
      }
      #pragma unroll
      for (int i = 0; i < 4; i++)
        #pragma unroll
        for (int j = 0; j < 4; j++)
          acc[i][j] = __builtin_amdgcn_mfma_f32_16x16x32_bf16(af[i], bf[j],
                                                              acc[i][j], 0, 0, 0);
    }
    __syncthreads();
  }

  // epilogues (C/D layout: col = lane&15, row = quad*4 + reg)
  if constexpr (MODE == 0) {
    float bb[4];
    #pragma unroll
    for (int j = 0; j < 4; j++) bb[j] = bias[n0 + wn * 64 + j * 16 + l15];
    #pragma unroll
    for (int i = 0; i < 4; i++)
      #pragma unroll
      for (int j = 0; j < 4; j++) {
        int col = wn * 64 + j * 16 + l15;
        #pragma unroll
        for (int r = 0; r < 4; r++) {
          int row = wm * 64 + i * 16 + quad * 4 + r;
          float v = acc[i][j][r] + bb[j];
          v = v > 0.f ? v : 0.f;
          sm.outT[row * 136 + col] = f2bf(v);
        }
      }
    __syncthreads();
    #pragma unroll
    for (int u = 0; u < 16; ++u) {
      int e = u * 256 + tid;
      int row = e >> 5, c4 = (e & 31) * 4;
      *(uint2*)&Hout[(size_t)(mt * 128 + row) * Nld + n0 + c4] =
          *(const uint2*)&sm.outT[row * 136 + c4];
    }
  } else if constexpr (MODE == 1) {
    if (tid < 128) sm.colsum[tid] = 0.f;
    __syncthreads();
    float bb[4];
    #pragma unroll
    for (int j = 0; j < 4; j++) bb[j] = bias[n0 + wn * 64 + j * 16 + l15];
    #pragma unroll
    for (int j = 0; j < 4; j++) {
      float v = 0.f;
      #pragma unroll
      for (int i = 0; i < 4; i++)
        #pragma unroll
        for (int r = 0; r < 4; r++) {
          int row = wm * 64 + i * 16 + quad * 4 + r;
          float t = acc[i][j][r] + bb[j];
          t = t > 0.f ? t : 0.f;
          v += (row < lenb) ? t : 0.f;
        }
      v += __shfl_xor(v, 16);
      v += __shfl_xor(v, 32);
      if (lane < 16) atomicAdd(&sm.colsum[wn * 64 + j * 16 + lane], v);
    }
    __syncthreads();
    if (tid < 128) atomicAdd(&Sout[(size_t)bidx * 4096 + n0 + tid], sm.colsum[tid]);
  } else {
    float bb[4];
    #pragma unroll
    for (int j = 0; j < 4; j++) bb[j] = bias[n0 + wn * 64 + j * 16 + l15];
    #pragma unroll
    for (int i = 0; i < 4; i++)
      #pragma unroll
      for (int j = 0; j < 4; j++) {
        int col = wn * 64 + j * 16 + l15;
        #pragma unroll
        for (int r = 0; r < 4; r++) {
          int row = wm * 64 + i * 16 + quad * 4 + r;
          if (row < 64) Fout[(size_t)row * Nld + n0 + col] = acc[i][j][r] + bb[j];
        }
      }
  }
}

// ---------------- host ----------------
extern "C" void kernel_launch(void* const* d_in, const int* in_sizes, int n_in,
                              void* d_out, int out_size, void* d_ws, size_t ws_size,
                              hipStream_t stream) {
  const float* x  = (const float*)d_in[0];
  const float* y  = (const float*)d_in[1];
  const int* mask = (const int*)d_in[2];
  const float* W1 = (const float*)d_in[3];
  const float* b1 = (const float*)d_in[4];
  const float* W2 = (const float*)d_in[5];
  const float* b2 = (const float*)d_in[6];
  const float* W3 = (const float*)d_in[7];
  const float* b3 = (const float*)d_in[8];
  float* out = (float*)d_out;

  char* ws = (char*)d_ws;
  size_t off = 0;
  auto alloc = [&](size_t bytes) {
    char* p = ws + off;
    off += (bytes + 255) & ~(size_t)255;
    return p;
  };
  int* lens = (int*)alloc(64 * 4);
  float* S  = (float*)alloc((size_t)128 * 4096 * 4);   // padded to 128 rows
  u16* Sn   = (u16*)alloc((size_t)128 * 4096 * 2);
  u16* W1T  = (u16*)alloc((size_t)4096 * 256 * 2);
  u16* W2T  = (u16*)alloc((size_t)4096 * 4096 * 2);
  u16* W3T  = (u16*)alloc((size_t)1024 * 4096 * 2);
  u16* Abuf = (u16*)alloc((size_t)32768 * 256 * 2);
  u16* H1   = (u16*)alloc((size_t)8192 * 4096 * 2);    // one M-chunk
  if (off > ws_size) return;  // workspace too small -> loud failure

  hipMemsetAsync(S, 0, (size_t)128 * 4096 * 4, stream);
  count_k<<<64, 64, 0, stream>>>(mask, lens);
  build_a<<<8192, 256, 0, stream>>>(x, y, Abuf);
  transpose_k<<<dim3(4096 / 32, 256 / 32), dim3(32, 8), 0, stream>>>(W1, W1T, 256, 4096);
  transpose_k<<<dim3(4096 / 32, 4096 / 32), dim3(32, 8), 0, stream>>>(W2, W2T, 4096, 4096);
  transpose_k<<<dim3(1024 / 32, 4096 / 32), dim3(32, 8), 0, stream>>>(W3, W3T, 4096, 1024);

  for (int c = 0; c < 4; ++c) {  // 8192-token chunks
    gemm_k<0><<<dim3(32, 64), 256, 0, stream>>>(
        Abuf + (size_t)c * 8192 * 256, 256, W1T, 256, b1, H1, nullptr, nullptr,
        lens, 256, 4096, c * 8192);
    gemm_k<1><<<dim3(32, 64), 256, 0, stream>>>(
        H1, 4096, W2T, 4096, b2, nullptr, S, nullptr,
        lens, 4096, 4096, c * 8192);
  }
  sn_k<<<512, 256, 0, stream>>>(S, lens, Sn);
  gemm_k<2><<<dim3(8, 1), 256, 0, stream>>>(
      Sn, 4096, W3T, 4096, b3, nullptr, nullptr, out, nullptr, 4096, 1024, 0);
}